// Round 1
// baseline (3287.384 us; speedup 1.0000x reference)
//
#include <hip/hip_runtime.h>
#include <math.h>

// LSTM anomaly-detection scan, B=256 T=1024 I=8 H=164 O=1, WL=0, THRESH=0.1.
// One block per batch element (256 blocks = 256 CUs), sequential t-loop inside.
// Thread j < 656 owns gate row j (i:0-163, f:164-327, g:328-491, o:492-655).
// W_hh cols 0..131 live in per-thread VGPRs (33 float4); W_ih (8 cols) and
// W_hh cols 132..163 live in LDS float4 "planes". h is broadcast per wave via
// 3 ds_read_b32 + v_readlane (VALU pipe, avoids the 43x ds_read_b128 LDS
// broadcast). pred is recomputed redundantly in every wave (shfl butterfly) so
// each step needs only 2 barriers.

namespace {
constexpr int kB = 256;
constexpr int kT = 1024;
constexpr int kI = 8;
constexpr int kH = 164;
constexpr int kG = 4 * kH;      // 656 gate rows
constexpr int kThreads = 704;   // 11 waves
constexpr int kRegK = 132;      // W_hh columns held in registers per thread
constexpr int kPlanes = 10;     // 2 planes W_ih + 8 planes W_hh cols 132..163
constexpr float kThresh = 0.1f;

__device__ __forceinline__ float rlane(float v, int l) {
    return __int_as_float(__builtin_amdgcn_readlane(__float_as_int(v), l));
}

__device__ __forceinline__ float hbroad(float vh0, float vh1, float vh2, int k) {
    return (k < 64) ? rlane(vh0, k)
         : (k < 128) ? rlane(vh1, k - 64)
                     : rlane(vh2, k - 128);
}
} // namespace

__global__ __launch_bounds__(kThreads) void lstm_anom_kernel(
    const float* __restrict__ x,     // (B,T,I)
    const float* __restrict__ Wih,   // (4H,I)
    const float* __restrict__ Whh,   // (4H,H)
    const float* __restrict__ bih,   // (4H)
    const float* __restrict__ bhh,   // (4H)
    const float* __restrict__ Wout,  // (O,H) = (1,164)
    const float* __restrict__ bout,  // (1)
    float* __restrict__ out)         // preds (B,T) then flags (B,T), fp32
{
    __shared__ float4 wp[kPlanes * kG];  // 10 * 656 * 16B = 105KB
    __shared__ float gates[kG];
    __shared__ float hlds[192];          // h[0..163]; 164..191 stay 0

    const int tid  = threadIdx.x;
    const int lane = tid & 63;
    const int b    = blockIdx.x;
    const int jj   = (tid < kG) ? tid : (kG - 1);   // clamp idle threads

    // ---- one-time init ----
    for (int i = tid; i < kPlanes * kG; i += kThreads) {
        int c = i / kG, r = i - c * kG;
        float4 v;
        if (c < 2) v = ((const float4*)(Wih + r * kI))[c];
        else       v = ((const float4*)(Whh + r * kH + kRegK))[c - 2];
        wp[i] = v;
    }
    if (tid < 192) hlds[tid] = 0.0f;

    float4 wreg[kRegK / 4];
    {
        const float4* wr = (const float4*)(Whh + (size_t)jj * kH);
        #pragma unroll
        for (int k = 0; k < kRegK / 4; ++k) wreg[k] = wr[k];
    }
    const float bsum = bih[jj] + bhh[jj];
    const float wo0 = Wout[lane];
    const float wo1 = Wout[64 + lane];
    const float wo2 = (128 + lane < kH) ? Wout[128 + lane] : 0.0f;
    const float bo  = bout[0];

    float cst = 0.0f;                       // cell state (threads tid<164)
    float vh0 = 0.0f, vh1 = 0.0f, vh2 = 0.0f;
    float pred = 0.0f;

    float* pred_out = out + (size_t)b * kT;
    float* flag_out = out + (size_t)kB * kT + (size_t)b * kT;
    const float* xb = x + (size_t)b * kT * kI;

    __syncthreads();

    for (int t = 0; t < kT; ++t) {
        // ---- x_t (wave-uniform global loads) + anomaly feedback ----
        const float4* xt = (const float4*)(xb + t * kI);
        float4 xa = xt[0];
        float4 xc = xt[1];
        bool anom = (t > 0) && (fabsf(pred - xa.x) > kThresh);
        float x0e = anom ? pred : xa.x;

        // ---- gate row jj pre-activation ----
        float acc = bsum;
        {
            float4 wi0 = wp[jj];
            float4 wi1 = wp[kG + jj];
            acc = fmaf(x0e,  wi0.x, acc);
            acc = fmaf(xa.y, wi0.y, acc);
            acc = fmaf(xa.z, wi0.z, acc);
            acc = fmaf(xa.w, wi0.w, acc);
            acc = fmaf(xc.x, wi1.x, acc);
            acc = fmaf(xc.y, wi1.y, acc);
            acc = fmaf(xc.z, wi1.z, acc);
            acc = fmaf(xc.w, wi1.w, acc);
        }
        #pragma unroll
        for (int kk = 0; kk < kRegK / 4; ++kk) {
            int k = kk * 4;
            float4 w = wreg[kk];
            acc = fmaf(hbroad(vh0, vh1, vh2, k + 0), w.x, acc);
            acc = fmaf(hbroad(vh0, vh1, vh2, k + 1), w.y, acc);
            acc = fmaf(hbroad(vh0, vh1, vh2, k + 2), w.z, acc);
            acc = fmaf(hbroad(vh0, vh1, vh2, k + 3), w.w, acc);
        }
        #pragma unroll
        for (int c = 0; c < 8; ++c) {
            float4 w = wp[(2 + c) * kG + jj];
            int k = kRegK + c * 4;
            acc = fmaf(hbroad(vh0, vh1, vh2, k + 0), w.x, acc);
            acc = fmaf(hbroad(vh0, vh1, vh2, k + 1), w.y, acc);
            acc = fmaf(hbroad(vh0, vh1, vh2, k + 2), w.z, acc);
            acc = fmaf(hbroad(vh0, vh1, vh2, k + 3), w.w, acc);
        }

        // ---- activation: rows [2H,3H) are tanh (g), rest sigmoid ----
        float av;
        if (jj < 2 * kH || jj >= 3 * kH) av = 1.0f / (1.0f + expf(-acc));
        else                             av = tanhf(acc);
        if (tid < kG) gates[tid] = av;
        __syncthreads();

        // ---- cell update (threads 0..163); av == i-gate here ----
        if (tid < kH) {
            float fv = gates[kH + tid];
            float gv = gates[2 * kH + tid];
            float ov = gates[3 * kH + tid];
            cst = fmaf(fv, cst, av * gv);
            float hv = ov * tanhf(cst);
            hlds[tid] = hv;
        }
        __syncthreads();

        // ---- reload h into lane regs; redundant per-wave pred reduce ----
        vh0 = hlds[lane];
        vh1 = hlds[64 + lane];
        vh2 = hlds[128 + lane];
        float p = fmaf(vh0, wo0, fmaf(vh1, wo1, vh2 * wo2));
        p += __shfl_xor(p, 32, 64);
        p += __shfl_xor(p, 16, 64);
        p += __shfl_xor(p, 8, 64);
        p += __shfl_xor(p, 4, 64);
        p += __shfl_xor(p, 2, 64);
        p += __shfl_xor(p, 1, 64);
        pred = p + bo;

        if (tid == 0) {
            pred_out[t] = pred;
            flag_out[t] = anom ? 1.0f : 0.0f;
        }
    }
}

extern "C" void kernel_launch(void* const* d_in, const int* in_sizes, int n_in,
                              void* d_out, int out_size, void* d_ws, size_t ws_size,
                              hipStream_t stream) {
    const float* x    = (const float*)d_in[0];
    const float* Wih  = (const float*)d_in[1];
    const float* Whh  = (const float*)d_in[2];
    const float* bih  = (const float*)d_in[3];
    const float* bhh  = (const float*)d_in[4];
    const float* Wout = (const float*)d_in[5];
    const float* bout = (const float*)d_in[6];
    lstm_anom_kernel<<<dim3(kB), dim3(kThreads), 0, stream>>>(
        x, Wih, Whh, bih, bhh, Wout, bout, (float*)d_out);
}

// Round 2
// 3016.996 us; speedup vs baseline: 1.0896x; 1.0896x over previous
//
#include <hip/hip_runtime.h>
#include <math.h>

// LSTM anomaly scan, B=256 T=1024 I=8 H=164 O=1, WL=0, THRESH=0.1.
// One block (704 thr = 11 waves) per batch element, sequential t-loop.
// Thread j owns gate row j. W_hh cols 0..111 in VGPRs (28 float4,
// __launch_bounds__(704,3) caps VGPR at ~170 so they stay resident);
// W_ih (8 cols) + W_hh cols 112..163 in LDS planes (162.7 KB).
// h broadcast via v_readlane from per-wave lane regs (every wave keeps the
// full c/h state redundantly: units lane, 64+lane, 128+lane), so each step
// needs ONE barrier (double-buffered gates). pred reduced with DPP row_shr/
// row_bcast (VALU) instead of ds_swizzle butterfly.

namespace {
constexpr int kB = 256;
constexpr int kT = 1024;
constexpr int kI = 8;
constexpr int kH = 164;
constexpr int kG = 4 * kH;            // 656
constexpr int kThreads = 704;         // 11 waves
constexpr int kRegK = 112;            // W_hh cols in VGPRs (28 float4)
constexpr int kLdsC = (kH - kRegK) / 4;   // 13 planes of W_hh tail
constexpr int kPlanes = 2 + kLdsC;        // 15
constexpr float kThresh = 0.1f;

__device__ __forceinline__ float rlane(float v, int l) {
    return __int_as_float(__builtin_amdgcn_readlane(__float_as_int(v), l));
}
__device__ __forceinline__ float hb(float h0, float h1, float h2, int k) {
    return (k < 64) ? rlane(h0, k)
         : (k < 128) ? rlane(h1, k - 64)
                     : rlane(h2, k - 128);
}
template <int CTRL>
__device__ __forceinline__ float dpp_add(float x) {
    int t = __builtin_amdgcn_update_dpp(0, __float_as_int(x), CTRL, 0xf, 0xf, true);
    return __int_as_float(t);
}
// full-wave sum, result broadcast via lane 63
__device__ __forceinline__ float wave_sum(float x) {
    x += dpp_add<0x111>(x);   // row_shr:1
    x += dpp_add<0x112>(x);   // row_shr:2
    x += dpp_add<0x114>(x);   // row_shr:4
    x += dpp_add<0x118>(x);   // row_shr:8
    x += dpp_add<0x142>(x);   // row_bcast:15
    x += dpp_add<0x143>(x);   // row_bcast:31
    return rlane(x, 63);
}
__device__ __forceinline__ float sigm(float x) {
    return 1.0f / (1.0f + __expf(-x));
}
__device__ __forceinline__ float tanh_f(float x) {
    x = fminf(fmaxf(x, -15.0f), 15.0f);
    float e = __expf(2.0f * x);
    return (e - 1.0f) / (e + 1.0f);
}
} // namespace

__global__ __launch_bounds__(kThreads, 3) void lstm_anom_kernel(
    const float* __restrict__ x,     // (B,T,I)
    const float* __restrict__ Wih,   // (4H,I)
    const float* __restrict__ Whh,   // (4H,H)
    const float* __restrict__ bih,   // (4H)
    const float* __restrict__ bhh,   // (4H)
    const float* __restrict__ Wout,  // (1,H)
    const float* __restrict__ bout,  // (1)
    float* __restrict__ out)         // preds (B,T) then flags (B,T)
{
    __shared__ float4 wp[kPlanes * kG];  // 15*656*16 = 157440 B
    __shared__ float gates[2][kG];       // 5248 B  (total 162688 B)

    const int tid  = threadIdx.x;
    const int lane = tid & 63;
    const int b    = blockIdx.x;
    const int jj   = (tid < kG) ? tid : (kG - 1);

    // ---- one-time staging ----
    for (int i = tid; i < kPlanes * kG; i += kThreads) {
        int c = i / kG, r = i - c * kG;
        float4 v;
        if (c < 2) v = ((const float4*)(Wih + r * kI))[c];
        else       v = ((const float4*)(Whh + r * kH + kRegK))[c - 2];
        wp[i] = v;
    }
    float4 wreg[kRegK / 4];
    {
        const float4* wr = (const float4*)(Whh + (size_t)jj * kH);
        #pragma unroll
        for (int k = 0; k < kRegK / 4; ++k) wreg[k] = wr[k];
    }
    const float bsum = bih[jj] + bhh[jj];
    const bool  is_tanh_row = (jj >= 2 * kH) && (jj < 3 * kH);
    const int   u2 = (lane < kH - 128) ? (128 + lane) : (kH - 1); // clamp
    const float wo0 = Wout[lane];
    const float wo1 = Wout[64 + lane];
    const float wo2 = (128 + lane < kH) ? Wout[128 + lane] : 0.0f;
    const float bo  = bout[0];

    // redundant per-wave state: units lane, 64+lane, u2
    float vc0 = 0.f, vc1 = 0.f, vc2 = 0.f;
    float vh0 = 0.f, vh1 = 0.f, vh2 = 0.f;
    float pred = 0.f;

    float* pred_out = out + (size_t)b * kT;
    float* flag_out = out + (size_t)kB * kT + (size_t)b * kT;
    const float* xb = x + (size_t)b * kT * kI;

    float4 xa = ((const float4*)xb)[0];
    float4 xc = ((const float4*)xb)[1];

    __syncthreads();

    for (int t = 0; t < kT; ++t) {
        // prefetch x[t+1] (issued before the FMA loop, consumed next iter)
        const float4* nx = (const float4*)(xb + (t + 1 < kT ? (t + 1) : t) * kI);
        float4 na = nx[0];
        float4 nc = nx[1];

        const bool  anom = (t > 0) && (fabsf(pred - xa.x) > kThresh);
        const float x0e  = anom ? pred : xa.x;

        // ---- gate row jj pre-activation: 4 independent accumulators ----
        float4 wi0 = wp[jj];
        float4 wi1 = wp[kG + jj];
        float a0 = fmaf(x0e,  wi0.x, bsum);
        float a1 = xa.y * wi0.y;
        float a2 = xa.z * wi0.z;
        float a3 = xa.w * wi0.w;
        a0 = fmaf(xc.x, wi1.x, a0);
        a1 = fmaf(xc.y, wi1.y, a1);
        a2 = fmaf(xc.z, wi1.z, a2);
        a3 = fmaf(xc.w, wi1.w, a3);
        #pragma unroll
        for (int kk = 0; kk < kRegK / 4; ++kk) {
            const int k = kk * 4;
            float4 w = wreg[kk];
            a0 = fmaf(hb(vh0, vh1, vh2, k + 0), w.x, a0);
            a1 = fmaf(hb(vh0, vh1, vh2, k + 1), w.y, a1);
            a2 = fmaf(hb(vh0, vh1, vh2, k + 2), w.z, a2);
            a3 = fmaf(hb(vh0, vh1, vh2, k + 3), w.w, a3);
        }
        #pragma unroll
        for (int c = 0; c < kLdsC; ++c) {
            const int k = kRegK + c * 4;
            float4 w = wp[(2 + c) * kG + jj];
            a0 = fmaf(hb(vh0, vh1, vh2, k + 0), w.x, a0);
            a1 = fmaf(hb(vh0, vh1, vh2, k + 1), w.y, a1);
            a2 = fmaf(hb(vh0, vh1, vh2, k + 2), w.z, a2);
            a3 = fmaf(hb(vh0, vh1, vh2, k + 3), w.w, a3);
        }
        const float acc = (a0 + a1) + (a2 + a3);
        const float av  = is_tanh_row ? tanh_f(acc) : sigm(acc);

        float* gw = gates[t & 1];
        if (tid < kG) gw[tid] = av;
        __syncthreads();

        // ---- redundant cell/h update in every wave (no 2nd barrier) ----
        const float* gb = gates[t & 1];
        float iv0 = gb[lane],          iv1 = gb[64 + lane],          iv2 = gb[u2];
        float fv0 = gb[kH + lane],     fv1 = gb[kH + 64 + lane],     fv2 = gb[kH + u2];
        float gv0 = gb[2*kH + lane],   gv1 = gb[2*kH + 64 + lane],   gv2 = gb[2*kH + u2];
        float ov0 = gb[3*kH + lane],   ov1 = gb[3*kH + 64 + lane],   ov2 = gb[3*kH + u2];
        vc0 = fmaf(fv0, vc0, iv0 * gv0);  vh0 = ov0 * tanh_f(vc0);
        vc1 = fmaf(fv1, vc1, iv1 * gv1);  vh1 = ov1 * tanh_f(vc1);
        vc2 = fmaf(fv2, vc2, iv2 * gv2);  vh2 = ov2 * tanh_f(vc2);

        // ---- pred (identical in every wave; DPP reduce, VALU only) ----
        float p = fmaf(vh0, wo0, fmaf(vh1, wo1, vh2 * wo2));
        pred = wave_sum(p) + bo;

        if (tid == 0) {
            pred_out[t] = pred;
            flag_out[t] = anom ? 1.0f : 0.0f;
        }
        xa = na;
        xc = nc;
    }
}

extern "C" void kernel_launch(void* const* d_in, const int* in_sizes, int n_in,
                              void* d_out, int out_size, void* d_ws, size_t ws_size,
                              hipStream_t stream) {
    const float* x    = (const float*)d_in[0];
    const float* Wih  = (const float*)d_in[1];
    const float* Whh  = (const float*)d_in[2];
    const float* bih  = (const float*)d_in[3];
    const float* bhh  = (const float*)d_in[4];
    const float* Wout = (const float*)d_in[5];
    const float* bout = (const float*)d_in[6];
    lstm_anom_kernel<<<dim3(kB), dim3(kThreads), 0, stream>>>(
        x, Wih, Whh, bih, bhh, Wout, bout, (float*)d_out);
}